// Round 1
// baseline (855.214 us; speedup 1.0000x reference)
//
#include <hip/hip_runtime.h>
#include <hip/hip_bf16.h>

// GINConv: out = relu(((1+eps)x + scatter_sum(x[src]->dst)) @ W1 + b1) @ W2 + b2
#define N_NODES 50000
#define F_IN    128
#define F_HID   512
#define N_EDGES 800000

// Coarse buckets: 64 nodes/bucket, 8 replicas (keyed by blockIdx&7 ~ XCD) per bucket.
// Sequential slot allocation per (bucket,replica) -> line-dense scatter writes.
#define NBKT 782          // ceil(50000/64)
#define RCAP 384          // per-cell capacity; mean ~128, Poisson tail negligible

typedef __bf16 bf16x2 __attribute__((ext_vector_type(2)));
typedef __bf16 bf16x4 __attribute__((ext_vector_type(4)));
typedef __bf16 bf16x8 __attribute__((ext_vector_type(8)));
typedef float  f32x4  __attribute__((ext_vector_type(4)));

// ---------------- prep: x->bf16 | W1,W2 -> MFMA B-fragment order | zero bucket counts ---
// B-fragment layout (HW-verified): lane holds B[k=(lane>>4)*8+j][n=lane&15].
#define NB_X 6250   // 50000*128/4/256
#define NB_W 32     // 8192 fragment-slots / 256
#define NB_CZ 98    // ceil(782*8*16 ints / int4 / 256) = ceil(25024/256)
__global__ __launch_bounds__(256) void prep(const float* __restrict__ x,
                                            const float* __restrict__ W1,
                                            const float* __restrict__ W2,
                                            __bf16* __restrict__ xb,
                                            __bf16* __restrict__ w1f,
                                            __bf16* __restrict__ w2f,
                                            int* __restrict__ bcnt) {
    int b = blockIdx.x, tid = threadIdx.x;
    if (b < NB_X) {
        int i = b * 256 + tid;
        float4 v = ((const float4*)x)[i];
        bf16x4 o = {(__bf16)v.x, (__bf16)v.y, (__bf16)v.z, (__bf16)v.w};
        ((bf16x4*)xb)[i] = o;
    } else if (b < NB_X + NB_W) {
        int t = (b - NB_X) * 256 + tid;
        int lane = t & 63, kk = (t >> 6) & 3, nt = (t >> 8) & 7, c = (t >> 11) & 3;
        int q = lane >> 4, l16 = lane & 15;
        bf16x8 o;
        #pragma unroll
        for (int j = 0; j < 8; ++j)
            o[j] = (__bf16)W1[(kk * 32 + q * 8 + j) * F_HID + c * 128 + nt * 16 + l16];
        *(bf16x8*)(w1f + (size_t)t * 8) = o;
    } else if (b < NB_X + 2 * NB_W) {
        int t = (b - NB_X - NB_W) * 256 + tid;
        int lane = t & 63, kk = (t >> 6) & 3, nt = (t >> 8) & 7, c = (t >> 11) & 3;
        int q = lane >> 4, l16 = lane & 15;
        bf16x8 o;
        #pragma unroll
        for (int j = 0; j < 8; ++j)
            o[j] = (__bf16)W2[(c * 128 + kk * 32 + q * 8 + j) * F_IN + nt * 16 + l16];
        *(bf16x8*)(w2f + (size_t)t * 8) = o;
    } else {
        int i = (b - NB_X - 2 * NB_W) * 256 + tid;   // zero 782*8 line-spaced counters
        if (i < NBKT * 8 * 4) {
            int4 z = {0, 0, 0, 0};
            ((int4*)bcnt)[i] = z;
        }
    }
}

// ---------------- bucket_fill: append (dstLocal,src) to (bucket, replica) cell ---------
// replica = blockIdx&7 (~XCD under round-robin dispatch): each cell's slots are written
// sequentially from one XCD -> 16 entries/line, single writeback. Payload 4B/edge.
__global__ __launch_bounds__(256) void bucket_fill(const int* __restrict__ ei,
                                                   int* __restrict__ bcnt,
                                                   int* __restrict__ entries) {
    int e = blockIdx.x * 256 + threadIdx.x;
    if (e >= N_EDGES) return;
    int src = ei[e];
    int dst = ei[N_EDGES + e];
    int cell = (dst >> 6) * 8 + (blockIdx.x & 7);
    int p = atomicAdd(&bcnt[cell * 16], 1);         // 64B-spaced counter
    if (p < RCAP)
        entries[cell * RCAP + p] = ((dst & 63) << 16) | src;   // src < 65536
}

// ---------------- bucket_agg: one block per bucket, LDS f32 accumulate ------------------
// accH layout de-interleaved: feature 2l -> accH[n*128+l], feature 2l+1 -> accH[n*128+64+l]
// so each ds_add_f32 wave-access hits bank lane%32 (2-way aliasing = free).
__global__ __launch_bounds__(256) void bucket_agg(const __bf16* __restrict__ xb,
                                                  const int* __restrict__ bcnt,
                                                  const int* __restrict__ entries,
                                                  const float* __restrict__ eps,
                                                  __bf16* __restrict__ agg) {
    __shared__ float accH[64 * 128];   // 32 KB
    const int tid = threadIdx.x;
    const int wave = tid >> 6, lane = tid & 63;
    const int bkt = blockIdx.x;

    #pragma unroll
    for (int i = 0; i < 8; ++i)
        ((f32x4*)accH)[i * 256 + tid] = (f32x4){0.f, 0.f, 0.f, 0.f};
    __syncthreads();

    // wave handles replicas 2*wave, 2*wave+1
    for (int rr = 0; rr < 2; ++rr) {
        int cell = bkt * 8 + wave * 2 + rr;
        int cnt = bcnt[cell * 16];
        cnt = cnt < RCAP ? cnt : RCAP;
        const int* ebase = entries + cell * RCAP;
        for (int i = 0; i < cnt; i += 64) {
            int rem = cnt - i;
            int m = rem < 64 ? rem : 64;
            int ve = ebase[i + (lane < m ? lane : 0)];   // coalesced entry chunk
            for (int j = 0; j < m; j += 4) {
                float f0[4], f1[4];
                int dl[4];
                bool act[4];
                #pragma unroll
                for (int u = 0; u < 4; ++u) {           // 4 loads in flight
                    act[u] = (j + u < m);
                    int en = __shfl(ve, j + u);
                    dl[u] = en >> 16;
                    int sn = en & 0xffff;
                    bf16x2 v;
                    if (act[u])
                        v = *(const bf16x2*)(xb + (size_t)sn * F_IN + lane * 2);
                    else
                        v = (bf16x2){(__bf16)0.f, (__bf16)0.f};
                    f0[u] = (float)v[0];
                    f1[u] = (float)v[1];
                }
                #pragma unroll
                for (int u = 0; u < 4; ++u)
                    if (act[u]) {
                        atomicAdd(&accH[dl[u] * 128 + lane], f0[u]);
                        atomicAdd(&accH[dl[u] * 128 + 64 + lane], f1[u]);
                    }
            }
        }
    }
    __syncthreads();

    // epilogue: agg[node] = accH[node] + (1+eps)*x[node], bf16 out
    const float s = 1.0f + eps[0];
    const int node0 = bkt * 64;
    for (int t = 0; t < 16; ++t) {
        int n = wave * 16 + t;
        int node = node0 + n;
        if (node >= N_NODES) break;
        float a0 = accH[n * 128 + lane];
        float a1 = accH[n * 128 + 64 + lane];
        bf16x2 self = *(const bf16x2*)(xb + (size_t)node * F_IN + lane * 2);
        bf16x2 o = {(__bf16)(a0 + s * (float)self[0]),
                    (__bf16)(a1 + s * (float)self[1])};
        *(bf16x2*)(agg + (size_t)node * F_IN + lane * 2) = o;
    }
}

// ---------------- fused MLP: out = relu(agg@W1+b1)@W2+b2 -------------------------------
// 32 rows/block. Weights in B-fragment order from global (L2-hot), h through 8 KB LDS in
// A-fragment order, 2 barriers/chunk.
__global__ __launch_bounds__(256) void fused_mlp(const __bf16* __restrict__ A,
                                                 const __bf16* __restrict__ w1f,
                                                 const __bf16* __restrict__ w2f,
                                                 const float* __restrict__ b1,
                                                 const float* __restrict__ b2,
                                                 float* __restrict__ out) {
    __shared__ __attribute__((aligned(16))) __bf16 Hb[4096];   // 8 KB, A-frag order

    const int tid  = threadIdx.x;
    const int wave = tid >> 6;
    const int lane = tid & 63;
    const int q = lane >> 4, l16 = lane & 15;
    const int m0 = blockIdx.x * 32;

    bf16x8 a_reg[2][4];
    #pragma unroll
    for (int mi = 0; mi < 2; ++mi) {
        int m = m0 + mi * 16 + l16;
        #pragma unroll
        for (int kk = 0; kk < 4; ++kk) {
            if (m < N_NODES)
                a_reg[mi][kk] = *(const bf16x8*)(A + (size_t)m * F_IN + kk * 32 + q * 8);
            else {
                __bf16 z = (__bf16)0.0f;
                a_reg[mi][kk] = (bf16x8){z, z, z, z, z, z, z, z};
            }
        }
    }

    f32x4 acc_o[2][2];
    #pragma unroll
    for (int ni = 0; ni < 2; ++ni) {
        float bv = b2[wave * 32 + ni * 16 + l16];
        f32x4 b4 = {bv, bv, bv, bv};
        acc_o[0][ni] = b4;
        acc_o[1][ni] = b4;
    }

    for (int c = 0; c < 4; ++c) {
        f32x4 acc_h[2][2];
        #pragma unroll
        for (int ni = 0; ni < 2; ++ni) {
            float bv = b1[c * 128 + wave * 32 + ni * 16 + l16];
            f32x4 b4 = {bv, bv, bv, bv};
            acc_h[0][ni] = b4;
            acc_h[1][ni] = b4;
        }
        #pragma unroll
        for (int kk = 0; kk < 4; ++kk) {
            bf16x8 bw[2];
            #pragma unroll
            for (int ni = 0; ni < 2; ++ni)
                bw[ni] = *(const bf16x8*)(w1f +
                    ((size_t)((c * 8 + wave * 2 + ni) * 4 + kk) << 9) + lane * 8);
            #pragma unroll
            for (int mi = 0; mi < 2; ++mi)
                #pragma unroll
                for (int ni = 0; ni < 2; ++ni)
                    acc_h[mi][ni] = __builtin_amdgcn_mfma_f32_16x16x32_bf16(
                        a_reg[mi][kk], bw[ni], acc_h[mi][ni], 0, 0, 0);
        }
        // relu -> Hb in A-fragment order (C elem (row=mi*16+q*4+r, col=wave*32+ni*16+l16))
        #pragma unroll
        for (int mi = 0; mi < 2; ++mi)
            #pragma unroll
            for (int ni = 0; ni < 2; ++ni)
                #pragma unroll
                for (int r = 0; r < 4; ++r)
                    Hb[(((mi * 4 + wave) * 64 + (ni * 2 + (l16 >> 3)) * 16 + q * 4 + r) << 3)
                       + (l16 & 7)] = (__bf16)fmaxf(acc_h[mi][ni][r], 0.0f);
        __syncthreads();

        #pragma unroll
        for (int kk = 0; kk < 4; ++kk) {
            bf16x8 am[2], bw[2];
            #pragma unroll
            for (int mi = 0; mi < 2; ++mi)
                am[mi] = *(const bf16x8*)&Hb[((mi * 4 + kk) * 64 + lane) << 3];
            #pragma unroll
            for (int ni = 0; ni < 2; ++ni)
                bw[ni] = *(const bf16x8*)(w2f +
                    ((size_t)((c * 8 + wave * 2 + ni) * 4 + kk) << 9) + lane * 8);
            #pragma unroll
            for (int mi = 0; mi < 2; ++mi)
                #pragma unroll
                for (int ni = 0; ni < 2; ++ni)
                    acc_o[mi][ni] = __builtin_amdgcn_mfma_f32_16x16x32_bf16(
                        am[mi], bw[ni], acc_o[mi][ni], 0, 0, 0);
        }
        __syncthreads();
    }

    #pragma unroll
    for (int mi = 0; mi < 2; ++mi)
        #pragma unroll
        for (int ni = 0; ni < 2; ++ni)
            #pragma unroll
            for (int r = 0; r < 4; ++r) {
                int m = m0 + mi * 16 + q * 4 + r;
                if (m < N_NODES)
                    out[(size_t)m * F_IN + wave * 32 + ni * 16 + l16] = acc_o[mi][ni][r];
            }
}

extern "C" void kernel_launch(void* const* d_in, const int* in_sizes, int n_in,
                              void* d_out, int out_size, void* d_ws, size_t ws_size,
                              hipStream_t stream) {
    const float* x   = (const float*)d_in[0];
    const int*   ei  = (const int*)d_in[1];
    const float* W1  = (const float*)d_in[2];
    const float* b1  = (const float*)d_in[3];
    const float* W2  = (const float*)d_in[4];
    const float* b2  = (const float*)d_in[5];
    const float* eps = (const float*)d_in[6];
    float* out = (float*)d_out;

    // ws layout (~36.1 MB):
    char* ws = (char*)d_ws;
    __bf16* xb   = (__bf16*)ws;                    // 12,800,000 B
    __bf16* agg  = (__bf16*)(ws + 12800000);       // 12,800,000 B
    __bf16* w1f  = (__bf16*)(ws + 25600000);       // 131,072 B
    __bf16* w2f  = (__bf16*)(ws + 25800000);       // 131,072 B
    int*    bcnt = (int*)(ws + 26000000);          // 782*8*64 B = 400,384 B
    int*    entries = (int*)(ws + 26500000);       // 782*8*384*4 B = 9,609,216 B

    prep<<<NB_X + 2 * NB_W + NB_CZ, 256, 0, stream>>>(x, W1, W2, xb, w1f, w2f, bcnt);
    bucket_fill<<<(N_EDGES + 255) / 256, 256, 0, stream>>>(ei, bcnt, entries);
    bucket_agg<<<NBKT, 256, 0, stream>>>(xb, bcnt, entries, eps, agg);
    fused_mlp<<<(N_NODES + 31) / 32, 256, 0, stream>>>(agg, w1f, w2f, b1, b2, out);
}

// Round 2
// 189.793 us; speedup vs baseline: 4.5060x; 4.5060x over previous
//
#include <hip/hip_runtime.h>
#include <hip/hip_bf16.h>

// GINConv: out = relu(((1+eps)x + scatter_sum(x[src]->dst)) @ W1 + b1) @ W2 + b2
#define N_NODES 50000
#define F_IN    128
#define F_HID   512
#define N_EDGES 800000

// Coarse buckets: 64 nodes/bucket, 8 replicas (keyed by blockIdx&7 ~ XCD) per bucket.
// bucket_fill appends line-densely; bucket_bin counting-sorts to per-node CSR;
// gather_agg does register accumulation one wave per node (round-0 proven structure).
#define NBKT 782          // ceil(50000/64)
#define RCAP 384          // per-cell capacity; mean ~128, Poisson tail negligible
#define BINCAP 1280       // per-bucket CSR capacity; mean 1024, +8 sigma

typedef __bf16 bf16x2 __attribute__((ext_vector_type(2)));
typedef __bf16 bf16x4 __attribute__((ext_vector_type(4)));
typedef __bf16 bf16x8 __attribute__((ext_vector_type(8)));
typedef float  f32x4  __attribute__((ext_vector_type(4)));

// ---------------- prep: x->bf16 | W1,W2 -> MFMA B-fragment order | zero bucket counts ---
// B-fragment layout (HW-verified): lane holds B[k=(lane>>4)*8+j][n=lane&15].
#define NB_X 6250   // 50000*128/4/256
#define NB_W 32     // 8192 fragment-slots / 256
#define NB_CZ 98    // ceil(782*8*16 ints / int4 / 256)
__global__ __launch_bounds__(256) void prep(const float* __restrict__ x,
                                            const float* __restrict__ W1,
                                            const float* __restrict__ W2,
                                            __bf16* __restrict__ xb,
                                            __bf16* __restrict__ w1f,
                                            __bf16* __restrict__ w2f,
                                            int* __restrict__ bcnt) {
    int b = blockIdx.x, tid = threadIdx.x;
    if (b < NB_X) {
        int i = b * 256 + tid;
        float4 v = ((const float4*)x)[i];
        bf16x4 o = {(__bf16)v.x, (__bf16)v.y, (__bf16)v.z, (__bf16)v.w};
        ((bf16x4*)xb)[i] = o;
    } else if (b < NB_X + NB_W) {
        int t = (b - NB_X) * 256 + tid;
        int lane = t & 63, kk = (t >> 6) & 3, nt = (t >> 8) & 7, c = (t >> 11) & 3;
        int q = lane >> 4, l16 = lane & 15;
        bf16x8 o;
        #pragma unroll
        for (int j = 0; j < 8; ++j)
            o[j] = (__bf16)W1[(kk * 32 + q * 8 + j) * F_HID + c * 128 + nt * 16 + l16];
        *(bf16x8*)(w1f + (size_t)t * 8) = o;
    } else if (b < NB_X + 2 * NB_W) {
        int t = (b - NB_X - NB_W) * 256 + tid;
        int lane = t & 63, kk = (t >> 6) & 3, nt = (t >> 8) & 7, c = (t >> 11) & 3;
        int q = lane >> 4, l16 = lane & 15;
        bf16x8 o;
        #pragma unroll
        for (int j = 0; j < 8; ++j)
            o[j] = (__bf16)W2[(c * 128 + kk * 32 + q * 8 + j) * F_IN + nt * 16 + l16];
        *(bf16x8*)(w2f + (size_t)t * 8) = o;
    } else {
        int i = (b - NB_X - 2 * NB_W) * 256 + tid;   // zero 782*8 line-spaced counters
        if (i < NBKT * 8 * 4) {
            int4 z = {0, 0, 0, 0};
            ((int4*)bcnt)[i] = z;
        }
    }
}

// ---------------- bucket_fill: append (dstLocal,src) to (bucket, replica) cell ---------
// replica = blockIdx&7 (~XCD under round-robin dispatch): each cell's slots are written
// sequentially, cell's counter + active lines stay hot in that XCD's L2.
__global__ __launch_bounds__(256) void bucket_fill(const int* __restrict__ ei,
                                                   int* __restrict__ bcnt,
                                                   int* __restrict__ entries) {
    int e = blockIdx.x * 256 + threadIdx.x;
    if (e >= N_EDGES) return;
    int src = ei[e];
    int dst = ei[N_EDGES + e];
    int cell = (dst >> 6) * 8 + (blockIdx.x & 7);
    int p = atomicAdd(&bcnt[cell * 16], 1);         // 64B-spaced counter
    if (p < RCAP)
        entries[cell * RCAP + p] = ((dst & 63) << 16) | src;   // src < 65536
}

// ---------------- bucket_bin: counting-sort bucket entries -> per-node CSR -------------
// One block per bucket. All global reads coalesced; scatter writes land in a 2.5KB
// L2-hot region. Outputs: binned[] (u16 src ids, CSR) and meta[node]=(deg<<20)|ofs.
__global__ __launch_bounds__(256) void bucket_bin(const int* __restrict__ bcnt,
                                                  const int* __restrict__ entries,
                                                  unsigned short* __restrict__ binned,
                                                  unsigned int* __restrict__ meta) {
    __shared__ int deg[64], base[64], cur[64];
    const int tid = threadIdx.x;
    const int bkt = blockIdx.x;

    if (tid < 64) deg[tid] = 0;
    __syncthreads();

    // pass 1: histogram by dstLocal
    #pragma unroll
    for (int r = 0; r < 8; ++r) {
        int cnt = bcnt[(bkt * 8 + r) * 16];
        cnt = cnt < RCAP ? cnt : RCAP;
        const int* eb = entries + (size_t)(bkt * 8 + r) * RCAP;
        for (int i = tid; i < cnt; i += 256)
            atomicAdd(&deg[eb[i] >> 16], 1);
    }
    __syncthreads();

    if (tid == 0) {
        int s = 0;
        for (int n = 0; n < 64; ++n) { base[n] = s; s += deg[n]; }
    }
    __syncthreads();

    if (tid < 64) {
        cur[tid] = base[tid];
        int node = bkt * 64 + tid;
        if (node < N_NODES)
            meta[node] = ((unsigned int)deg[tid] << 20) | (unsigned int)(bkt * BINCAP + base[tid]);
    }
    __syncthreads();

    // pass 2: scatter src ids into CSR order (entries are L2-hot from pass 1)
    #pragma unroll
    for (int r = 0; r < 8; ++r) {
        int cnt = bcnt[(bkt * 8 + r) * 16];
        cnt = cnt < RCAP ? cnt : RCAP;
        const int* eb = entries + (size_t)(bkt * 8 + r) * RCAP;
        for (int i = tid; i < cnt; i += 256) {
            int en = eb[i];
            int p = atomicAdd(&cur[en >> 16], 1);
            if (p < BINCAP)
                binned[(size_t)bkt * BINCAP + p] = (unsigned short)(en & 0xffff);
        }
    }
}

// ---------------- gather_agg: one wave per node, quad-parallel over CSR ----------------
// Lane=(q,l16): l16*8 = 16B feature chunk; quad q processes CSR entries j==q (mod 4),
// 2-unrolled (8 row-loads in flight per wave). Cross-quad: 2x shfl_xor; q==0 writes.
__global__ __launch_bounds__(256) void gather_agg(const __bf16* __restrict__ xb,
                                                  const unsigned int* __restrict__ meta,
                                                  const unsigned short* __restrict__ binned,
                                                  const float* __restrict__ eps,
                                                  __bf16* __restrict__ agg) {
    int node = blockIdx.x * 4 + (threadIdx.x >> 6);
    int lane = threadIdx.x & 63;
    int q = lane >> 4, l16 = lane & 15;
    if (node >= N_NODES) return;
    const float s = 1.0f + eps[0];

    unsigned int m = meta[node];
    int deg = m >> 20;
    const unsigned short* bin = binned + (m & 0xFFFFF);

    float acc[8];
    #pragma unroll
    for (int i = 0; i < 8; ++i) acc[i] = 0.0f;
    if (q == 0) {
        bf16x8 self = *(const bf16x8*)(xb + (size_t)node * F_IN + l16 * 8);
        #pragma unroll
        for (int i = 0; i < 8; ++i) acc[i] = (float)self[i] * s;
    }

    int j = q;
    for (; j + 4 < deg; j += 8) {
        int s0 = bin[j];
        int s1 = bin[j + 4];
        bf16x8 v0 = *(const bf16x8*)(xb + (size_t)s0 * F_IN + l16 * 8);
        bf16x8 v1 = *(const bf16x8*)(xb + (size_t)s1 * F_IN + l16 * 8);
        #pragma unroll
        for (int i = 0; i < 8; ++i) acc[i] += (float)v0[i] + (float)v1[i];
    }
    if (j < deg) {
        bf16x8 v = *(const bf16x8*)(xb + (size_t)bin[j] * F_IN + l16 * 8);
        #pragma unroll
        for (int i = 0; i < 8; ++i) acc[i] += (float)v[i];
    }

    #pragma unroll
    for (int i = 0; i < 8; ++i) {
        acc[i] += __shfl_xor(acc[i], 16);
        acc[i] += __shfl_xor(acc[i], 32);
    }
    if (q == 0) {
        bf16x8 o;
        #pragma unroll
        for (int i = 0; i < 8; ++i) o[i] = (__bf16)acc[i];
        *(bf16x8*)(agg + (size_t)node * F_IN + l16 * 8) = o;
    }
}

// ---------------- fused MLP: out = relu(agg@W1+b1)@W2+b2 -------------------------------
// 32 rows/block. Weights in B-fragment order from global (L2-hot), h through 8 KB LDS in
// A-fragment order, 2 barriers/chunk.
__global__ __launch_bounds__(256) void fused_mlp(const __bf16* __restrict__ A,
                                                 const __bf16* __restrict__ w1f,
                                                 const __bf16* __restrict__ w2f,
                                                 const float* __restrict__ b1,
                                                 const float* __restrict__ b2,
                                                 float* __restrict__ out) {
    __shared__ __attribute__((aligned(16))) __bf16 Hb[4096];   // 8 KB, A-frag order

    const int tid  = threadIdx.x;
    const int wave = tid >> 6;
    const int lane = tid & 63;
    const int q = lane >> 4, l16 = lane & 15;
    const int m0 = blockIdx.x * 32;

    bf16x8 a_reg[2][4];
    #pragma unroll
    for (int mi = 0; mi < 2; ++mi) {
        int m = m0 + mi * 16 + l16;
        #pragma unroll
        for (int kk = 0; kk < 4; ++kk) {
            if (m < N_NODES)
                a_reg[mi][kk] = *(const bf16x8*)(A + (size_t)m * F_IN + kk * 32 + q * 8);
            else {
                __bf16 z = (__bf16)0.0f;
                a_reg[mi][kk] = (bf16x8){z, z, z, z, z, z, z, z};
            }
        }
    }

    f32x4 acc_o[2][2];
    #pragma unroll
    for (int ni = 0; ni < 2; ++ni) {
        float bv = b2[wave * 32 + ni * 16 + l16];
        f32x4 b4 = {bv, bv, bv, bv};
        acc_o[0][ni] = b4;
        acc_o[1][ni] = b4;
    }

    for (int c = 0; c < 4; ++c) {
        f32x4 acc_h[2][2];
        #pragma unroll
        for (int ni = 0; ni < 2; ++ni) {
            float bv = b1[c * 128 + wave * 32 + ni * 16 + l16];
            f32x4 b4 = {bv, bv, bv, bv};
            acc_h[0][ni] = b4;
            acc_h[1][ni] = b4;
        }
        #pragma unroll
        for (int kk = 0; kk < 4; ++kk) {
            bf16x8 bw[2];
            #pragma unroll
            for (int ni = 0; ni < 2; ++ni)
                bw[ni] = *(const bf16x8*)(w1f +
                    ((size_t)((c * 8 + wave * 2 + ni) * 4 + kk) << 9) + lane * 8);
            #pragma unroll
            for (int mi = 0; mi < 2; ++mi)
                #pragma unroll
                for (int ni = 0; ni < 2; ++ni)
                    acc_h[mi][ni] = __builtin_amdgcn_mfma_f32_16x16x32_bf16(
                        a_reg[mi][kk], bw[ni], acc_h[mi][ni], 0, 0, 0);
        }
        // relu -> Hb in A-fragment order (C elem (row=mi*16+q*4+r, col=wave*32+ni*16+l16))
        #pragma unroll
        for (int mi = 0; mi < 2; ++mi)
            #pragma unroll
            for (int ni = 0; ni < 2; ++ni)
                #pragma unroll
                for (int r = 0; r < 4; ++r)
                    Hb[(((mi * 4 + wave) * 64 + (ni * 2 + (l16 >> 3)) * 16 + q * 4 + r) << 3)
                       + (l16 & 7)] = (__bf16)fmaxf(acc_h[mi][ni][r], 0.0f);
        __syncthreads();

        #pragma unroll
        for (int kk = 0; kk < 4; ++kk) {
            bf16x8 am[2], bw[2];
            #pragma unroll
            for (int mi = 0; mi < 2; ++mi)
                am[mi] = *(const bf16x8*)&Hb[((mi * 4 + kk) * 64 + lane) << 3];
            #pragma unroll
            for (int ni = 0; ni < 2; ++ni)
                bw[ni] = *(const bf16x8*)(w2f +
                    ((size_t)((c * 8 + wave * 2 + ni) * 4 + kk) << 9) + lane * 8);
            #pragma unroll
            for (int mi = 0; mi < 2; ++mi)
                #pragma unroll
                for (int ni = 0; ni < 2; ++ni)
                    acc_o[mi][ni] = __builtin_amdgcn_mfma_f32_16x16x32_bf16(
                        am[mi], bw[ni], acc_o[mi][ni], 0, 0, 0);
        }
        __syncthreads();
    }

    #pragma unroll
    for (int mi = 0; mi < 2; ++mi)
        #pragma unroll
        for (int ni = 0; ni < 2; ++ni)
            #pragma unroll
            for (int r = 0; r < 4; ++r) {
                int m = m0 + mi * 16 + q * 4 + r;
                if (m < N_NODES)
                    out[(size_t)m * F_IN + wave * 32 + ni * 16 + l16] = acc_o[mi][ni][r];
            }
}

extern "C" void kernel_launch(void* const* d_in, const int* in_sizes, int n_in,
                              void* d_out, int out_size, void* d_ws, size_t ws_size,
                              hipStream_t stream) {
    const float* x   = (const float*)d_in[0];
    const int*   ei  = (const int*)d_in[1];
    const float* W1  = (const float*)d_in[2];
    const float* b1  = (const float*)d_in[3];
    const float* W2  = (const float*)d_in[4];
    const float* b2  = (const float*)d_in[5];
    const float* eps = (const float*)d_in[6];
    float* out = (float*)d_out;

    // ws layout (~40.4 MB):
    char* ws = (char*)d_ws;
    __bf16* xb   = (__bf16*)ws;                              // 12,800,000 B
    __bf16* agg  = (__bf16*)(ws + 12800000);                 // 12,800,000 B
    __bf16* w1f  = (__bf16*)(ws + 25600000);                 // 131,072 B
    __bf16* w2f  = (__bf16*)(ws + 25800000);                 // 131,072 B
    int*    bcnt = (int*)(ws + 26000000);                    // 782*8*64 B = 400,384 B
    int*    entries = (int*)(ws + 26500000);                 // 782*8*384*4 B = 9,609,216 B
    unsigned int*   meta   = (unsigned int*)(ws + 36200000); // 50000*4 B = 200,000 B
    unsigned short* binned = (unsigned short*)(ws + 36400000); // 782*1280*2 B = 2,001,920 B

    prep<<<NB_X + 2 * NB_W + NB_CZ, 256, 0, stream>>>(x, W1, W2, xb, w1f, w2f, bcnt);
    bucket_fill<<<(N_EDGES + 255) / 256, 256, 0, stream>>>(ei, bcnt, entries);
    bucket_bin<<<NBKT, 256, 0, stream>>>(bcnt, entries, binned, meta);
    gather_agg<<<(N_NODES + 3) / 4, 256, 0, stream>>>(xb, meta, binned, eps, agg);
    fused_mlp<<<(N_NODES + 31) / 32, 256, 0, stream>>>(agg, w1f, w2f, b1, b2, out);
}

// Round 3
// 187.446 us; speedup vs baseline: 4.5625x; 1.0125x over previous
//
#include <hip/hip_runtime.h>
#include <hip/hip_bf16.h>

// GINConv: out = relu(((1+eps)x + scatter_sum(x[src]->dst)) @ W1 + b1) @ W2 + b2
#define N_NODES 50000
#define F_IN    128
#define F_HID   512
#define N_EDGES 800000

// Coarse buckets: 64 nodes/bucket, 8 replicas (keyed by blockIdx&7 ~ XCD) per bucket.
// bucket_fill appends line-densely; gin_fused (1 block/bucket, 512 thr) does
// LDS counting-sort -> register gather -> 64-row MFMA MLP, all through LDS.
#define NBKT 782          // ceil(50000/64)
#define RCAP 384          // per-cell capacity; mean ~128, Poisson tail negligible
#define BINCAP 1280       // per-bucket CSR capacity; mean 1024, +8 sigma

typedef __bf16 bf16x2 __attribute__((ext_vector_type(2)));
typedef __bf16 bf16x4 __attribute__((ext_vector_type(4)));
typedef __bf16 bf16x8 __attribute__((ext_vector_type(8)));
typedef float  f32x4  __attribute__((ext_vector_type(4)));

// ---------------- prep: x->bf16 | W1,W2 -> MFMA B-fragment order | zero bucket counts ---
// B-fragment layout (HW-verified): lane holds B[k=(lane>>4)*8+j][n=lane&15].
#define NB_X 6250   // 50000*128/4/256
#define NB_W 32     // 8192 fragment-slots / 256
#define NB_CZ 98    // ceil(782*8*16 ints / int4 / 256)
__global__ __launch_bounds__(256) void prep(const float* __restrict__ x,
                                            const float* __restrict__ W1,
                                            const float* __restrict__ W2,
                                            __bf16* __restrict__ xb,
                                            __bf16* __restrict__ w1f,
                                            __bf16* __restrict__ w2f,
                                            int* __restrict__ bcnt) {
    int b = blockIdx.x, tid = threadIdx.x;
    if (b < NB_X) {
        int i = b * 256 + tid;
        float4 v = ((const float4*)x)[i];
        bf16x4 o = {(__bf16)v.x, (__bf16)v.y, (__bf16)v.z, (__bf16)v.w};
        ((bf16x4*)xb)[i] = o;
    } else if (b < NB_X + NB_W) {
        int t = (b - NB_X) * 256 + tid;
        int lane = t & 63, kk = (t >> 6) & 3, nt = (t >> 8) & 7, c = (t >> 11) & 3;
        int q = lane >> 4, l16 = lane & 15;
        bf16x8 o;
        #pragma unroll
        for (int j = 0; j < 8; ++j)
            o[j] = (__bf16)W1[(kk * 32 + q * 8 + j) * F_HID + c * 128 + nt * 16 + l16];
        *(bf16x8*)(w1f + (size_t)t * 8) = o;
    } else if (b < NB_X + 2 * NB_W) {
        int t = (b - NB_X - NB_W) * 256 + tid;
        int lane = t & 63, kk = (t >> 6) & 3, nt = (t >> 8) & 7, c = (t >> 11) & 3;
        int q = lane >> 4, l16 = lane & 15;
        bf16x8 o;
        #pragma unroll
        for (int j = 0; j < 8; ++j)
            o[j] = (__bf16)W2[(c * 128 + kk * 32 + q * 8 + j) * F_IN + nt * 16 + l16];
        *(bf16x8*)(w2f + (size_t)t * 8) = o;
    } else {
        int i = (b - NB_X - 2 * NB_W) * 256 + tid;   // zero 782*8 line-spaced counters
        if (i < NBKT * 8 * 4) {
            int4 z = {0, 0, 0, 0};
            ((int4*)bcnt)[i] = z;
        }
    }
}

// ---------------- bucket_fill: append (dstLocal,src) to (bucket, replica) cell ---------
// replica = blockIdx&7 (~XCD under round-robin dispatch): each cell's slots are written
// sequentially, cell's counter + active lines stay hot in that XCD's L2.
__global__ __launch_bounds__(256) void bucket_fill(const int* __restrict__ ei,
                                                   int* __restrict__ bcnt,
                                                   int* __restrict__ entries) {
    int e = blockIdx.x * 256 + threadIdx.x;
    if (e >= N_EDGES) return;
    int src = ei[e];
    int dst = ei[N_EDGES + e];
    int cell = (dst >> 6) * 8 + (blockIdx.x & 7);
    int p = atomicAdd(&bcnt[cell * 16], 1);         // 64B-spaced counter
    if (p < RCAP)
        entries[cell * RCAP + p] = ((dst & 63) << 16) | src;   // src < 65536
}

// ---------------- gin_fused: bin (LDS) -> gather (regs) -> 64-row MFMA MLP -------------
// One block (512 thr, 8 waves) per bucket.
// Phase 0: wave r drains replica cell r into registers (<=6 entries/lane), LDS histogram,
//          wave-0 shfl prefix, scatter to LDS CSR bin16[].
// Phase 1: wave handles 8 nodes; quad-split register gather (bf16x8 rows, shfl-reduce);
//          writes A-tile to LDS in A-fragment order, XOR-swizzled (byte ^= (l16&7)<<4)
//          so frag writes and per-quad ds_read_b128 are both 2-way (free).
// Phase 2: 64-row MFMA: wave=(wr,wc)=(wave>>2, wave&3); H via 16KB LDS in A-frag order.
__global__ __launch_bounds__(512) void gin_fused(const __bf16* __restrict__ xb,
                                                 const int* __restrict__ bcnt,
                                                 const int* __restrict__ entries,
                                                 const float* __restrict__ eps,
                                                 const __bf16* __restrict__ w1f,
                                                 const __bf16* __restrict__ w2f,
                                                 const float* __restrict__ b1,
                                                 const float* __restrict__ b2,
                                                 float* __restrict__ out) {
    __shared__ int degs[64], bases[64], curs[64];
    __shared__ unsigned short bin16[BINCAP];
    __shared__ __attribute__((aligned(16))) __bf16 As[8192];   // 16 KB A-tile, swizzled
    __shared__ __attribute__((aligned(16))) __bf16 Hb[8192];   // 16 KB H-tile, A-frag order

    const int tid = threadIdx.x;
    const int wave = tid >> 6, lane = tid & 63;
    const int q = lane >> 4, l16 = lane & 15;
    const int bkt = blockIdx.x;

    // ---- phase 0: counting-sort bucket entries into LDS CSR ----
    if (tid < 64) degs[tid] = 0;
    __syncthreads();

    int cnt = bcnt[(bkt * 8 + wave) * 16];
    cnt = cnt < RCAP ? cnt : RCAP;
    const int* eb = entries + (size_t)(bkt * 8 + wave) * RCAP;
    int ev[6];                                   // RCAP/64 = 6; static-indexed (unrolled)
    #pragma unroll
    for (int u = 0; u < 6; ++u) {
        int i = lane + u * 64;
        int en = (i < cnt) ? eb[i] : -1;
        ev[u] = en;
        if (en >= 0) atomicAdd(&degs[en >> 16], 1);
    }
    __syncthreads();

    if (wave == 0) {                             // 64-lane shfl inclusive scan
        int d = degs[lane];
        int sum = d;
        #pragma unroll
        for (int off = 1; off < 64; off <<= 1) {
            int t = __shfl_up(sum, off);
            if (lane >= off) sum += t;
        }
        bases[lane] = sum - d;
        curs[lane]  = sum - d;
    }
    __syncthreads();

    #pragma unroll
    for (int u = 0; u < 6; ++u) {
        int en = ev[u];
        if (en >= 0) {
            int p = atomicAdd(&curs[en >> 16], 1);
            if (p < BINCAP) bin16[p] = (unsigned short)(en & 0xffff);
        }
    }
    __syncthreads();

    // ---- phase 1: register gather, write A-tile to LDS (A-frag order, swizzled) ----
    const float s = 1.0f + eps[0];
    for (int t = 0; t < 8; ++t) {
        int n = wave * 8 + t;
        int node = bkt * 64 + n;
        if (node >= N_NODES) break;
        int dg = degs[n], b0 = bases[n];
        int end = b0 + dg;
        end = end < BINCAP ? end : BINCAP;

        float acc[8];
        #pragma unroll
        for (int i = 0; i < 8; ++i) acc[i] = 0.0f;
        if (q == 0) {
            bf16x8 self = *(const bf16x8*)(xb + (size_t)node * F_IN + l16 * 8);
            #pragma unroll
            for (int i = 0; i < 8; ++i) acc[i] = (float)self[i] * s;
        }

        int j = b0 + q;
        for (; j + 4 < end; j += 8) {
            int s0 = bin16[j];
            int s1 = bin16[j + 4];
            bf16x8 r0 = *(const bf16x8*)(xb + (size_t)s0 * F_IN + l16 * 8);
            bf16x8 r1 = *(const bf16x8*)(xb + (size_t)s1 * F_IN + l16 * 8);
            #pragma unroll
            for (int i = 0; i < 8; ++i) acc[i] += (float)r0[i] + (float)r1[i];
        }
        if (j < end) {
            bf16x8 r0 = *(const bf16x8*)(xb + (size_t)bin16[j] * F_IN + l16 * 8);
            #pragma unroll
            for (int i = 0; i < 8; ++i) acc[i] += (float)r0[i];
        }

        #pragma unroll
        for (int i = 0; i < 8; ++i) {
            acc[i] += __shfl_xor(acc[i], 16);
            acc[i] += __shfl_xor(acc[i], 32);
        }
        if (lane < 16) {
            // lane holds features lane*8..+7 of row n -> one A-frag 16B slot
            int g = n >> 4, r16 = n & 15;
            bf16x8 o;
            #pragma unroll
            for (int i = 0; i < 8; ++i) o[i] = (__bf16)acc[i];
            int byte = (g * 16 + lane) * 256 + r16 * 16;
            byte ^= (lane & 7) << 4;
            *(bf16x8*)((char*)As + byte) = o;
        }
    }
    __syncthreads();

    // ---- phase 2: 64-row MFMA MLP ----
    const int wr = wave >> 2, wc = wave & 3;

    f32x4 acc_o[2][2];
    #pragma unroll
    for (int ni = 0; ni < 2; ++ni) {
        float bv = b2[wc * 32 + ni * 16 + l16];
        f32x4 b4 = {bv, bv, bv, bv};
        acc_o[0][ni] = b4;
        acc_o[1][ni] = b4;
    }

    for (int c = 0; c < 4; ++c) {
        f32x4 acc_h[2][2];
        #pragma unroll
        for (int ni = 0; ni < 2; ++ni) {
            float bv = b1[c * 128 + wc * 32 + ni * 16 + l16];
            f32x4 b4 = {bv, bv, bv, bv};
            acc_h[0][ni] = b4;
            acc_h[1][ni] = b4;
        }
        #pragma unroll
        for (int kk = 0; kk < 4; ++kk) {
            bf16x8 am[2], bw[2];
            #pragma unroll
            for (int mi = 0; mi < 2; ++mi) {
                int g = wr * 2 + mi;
                int byte = ((g * 4 + kk) * 4 + q) * 256 + l16 * 16;
                byte ^= ((kk * 4 + q) & 7) << 4;
                am[mi] = *(const bf16x8*)((const char*)As + byte);
            }
            #pragma unroll
            for (int ni = 0; ni < 2; ++ni)
                bw[ni] = *(const bf16x8*)(w1f +
                    ((size_t)((c * 8 + wc * 2 + ni) * 4 + kk) << 9) + lane * 8);
            #pragma unroll
            for (int mi = 0; mi < 2; ++mi)
                #pragma unroll
                for (int ni = 0; ni < 2; ++ni)
                    acc_h[mi][ni] = __builtin_amdgcn_mfma_f32_16x16x32_bf16(
                        am[mi], bw[ni], acc_h[mi][ni], 0, 0, 0);
        }
        // relu -> Hb in A-frag order: C elem (row=wr*32+mi*16+q*4+r, col=wc*32+ni*16+l16)
        #pragma unroll
        for (int mi = 0; mi < 2; ++mi) {
            int g = wr * 2 + mi;
            #pragma unroll
            for (int ni = 0; ni < 2; ++ni)
                #pragma unroll
                for (int r = 0; r < 4; ++r)
                    Hb[(((g * 4 + wc) * 64 + (ni * 2 + (l16 >> 3)) * 16 + q * 4 + r) << 3)
                       + (l16 & 7)] = (__bf16)fmaxf(acc_h[mi][ni][r], 0.0f);
        }
        __syncthreads();

        #pragma unroll
        for (int kk = 0; kk < 4; ++kk) {
            bf16x8 am[2], bw[2];
            #pragma unroll
            for (int mi = 0; mi < 2; ++mi)
                am[mi] = *(const bf16x8*)&Hb[(((wr * 2 + mi) * 4 + kk) * 64 + lane) << 3];
            #pragma unroll
            for (int ni = 0; ni < 2; ++ni)
                bw[ni] = *(const bf16x8*)(w2f +
                    ((size_t)((c * 8 + wc * 2 + ni) * 4 + kk) << 9) + lane * 8);
            #pragma unroll
            for (int mi = 0; mi < 2; ++mi)
                #pragma unroll
                for (int ni = 0; ni < 2; ++ni)
                    acc_o[mi][ni] = __builtin_amdgcn_mfma_f32_16x16x32_bf16(
                        am[mi], bw[ni], acc_o[mi][ni], 0, 0, 0);
        }
        __syncthreads();
    }

    const int m0 = bkt * 64;
    #pragma unroll
    for (int mi = 0; mi < 2; ++mi)
        #pragma unroll
        for (int ni = 0; ni < 2; ++ni)
            #pragma unroll
            for (int r = 0; r < 4; ++r) {
                int m = m0 + wr * 32 + mi * 16 + q * 4 + r;
                if (m < N_NODES)
                    out[(size_t)m * F_IN + wc * 32 + ni * 16 + l16] = acc_o[mi][ni][r];
            }
}

extern "C" void kernel_launch(void* const* d_in, const int* in_sizes, int n_in,
                              void* d_out, int out_size, void* d_ws, size_t ws_size,
                              hipStream_t stream) {
    const float* x   = (const float*)d_in[0];
    const int*   ei  = (const int*)d_in[1];
    const float* W1  = (const float*)d_in[2];
    const float* b1  = (const float*)d_in[3];
    const float* W2  = (const float*)d_in[4];
    const float* b2  = (const float*)d_in[5];
    const float* eps = (const float*)d_in[6];
    float* out = (float*)d_out;

    // ws layout (~23.4 MB):
    char* ws = (char*)d_ws;
    __bf16* xb   = (__bf16*)ws;                    // 12,800,000 B
    __bf16* w1f  = (__bf16*)(ws + 12800000);       // 131,072 B
    __bf16* w2f  = (__bf16*)(ws + 13000000);       // 131,072 B
    int*    bcnt = (int*)(ws + 13200000);          // 782*8*64 B = 400,384 B
    int*    entries = (int*)(ws + 13700000);       // 782*8*384*4 B = 9,609,216 B

    prep<<<NB_X + 2 * NB_W + NB_CZ, 256, 0, stream>>>(x, W1, W2, xb, w1f, w2f, bcnt);
    bucket_fill<<<(N_EDGES + 255) / 256, 256, 0, stream>>>(ei, bcnt, entries);
    gin_fused<<<NBKT, 512, 0, stream>>>(xb, bcnt, entries, eps, w1f, w2f, b1, b2, out);
}